// Round 1
// baseline (94542.548 us; speedup 1.0000x reference)
//
#include <hip/hip_runtime.h>
#include <math.h>

#define S_LEN 131072
#define H 100
#define G 400   // 4*H

typedef float v2f __attribute__((ext_vector_type(2)));
typedef float v4f __attribute__((ext_vector_type(4)));

__device__ __forceinline__ float sigmoid_fast(float x) {
    return 1.0f / (1.0f + __expf(-x));
}
__device__ __forceinline__ float tanh_fast(float x) {
    // 2*sigmoid(2x) - 1 ; saturates correctly for large |x|
    return 2.0f / (1.0f + __expf(-2.0f * x)) - 1.0f;
}

__global__ __launch_bounds__(448) void lstm_seq_kernel(
    const float* __restrict__ x,      // [S]
    const float* __restrict__ W_ih,   // [400]  (400x1)
    const float* __restrict__ W_hh,   // [400,100] row-major
    const float* __restrict__ b_ih,   // [400]
    const float* __restrict__ b_hh,   // [400]
    const float* __restrict__ W_out,  // [100]  (1x100)
    const float* __restrict__ b_out,  // [1]
    float* __restrict__ out)          // [1]
{
    __shared__ __align__(16) float h_lds[112];       // hidden state (100 used)
    __shared__ __align__(16) float act_lds[4][112];  // activated gates i,f,g,o

    const int t = threadIdx.x;

    // ---- load this thread's W_hh row into registers (t < 400) ----
    v2f w[50];
    float wih = 0.0f, bsum = 0.0f;
    if (t < G) {
        #pragma unroll
        for (int j = 0; j < 50; ++j) {
            w[j].x = W_hh[t * H + 2 * j];
            w[j].y = W_hh[t * H + 2 * j + 1];
        }
        wih  = W_ih[t];
        bsum = b_ih[t] + b_hh[t];
    }

    float c = 0.0f;                    // cell state, owned by threads 0..99
    if (t < H) h_lds[t] = 0.0f;
    __syncthreads();

    const int gidx = t / H;            // which gate block: 0=i 1=f 2=g 3=o

    for (int step = 0; step < S_LEN; ++step) {
        float xv = x[step];            // wave-uniform -> scalar load, hidden under matvec

        // ---- matvec: gate_r = W_hh[r,:] @ h + x*W_ih[r] + b ----
        v2f acc0 = {0.0f, 0.0f};
        v2f acc1 = {0.0f, 0.0f};
        if (t < G) {
            #pragma unroll
            for (int j = 0; j < 25; ++j) {
                v4f h4 = *(const v4f*)&h_lds[4 * j];   // LDS broadcast read
                v2f hlo = {h4.x, h4.y};
                v2f hhi = {h4.z, h4.w};
                acc0 = __builtin_elementwise_fma(w[2 * j],     hlo, acc0);
                acc1 = __builtin_elementwise_fma(w[2 * j + 1], hhi, acc1);
            }
            float gate = (acc0.x + acc0.y) + (acc1.x + acc1.y)
                       + xv * wih + bsum;
            // activate in the parallel phase (distributes the transcendentals)
            float a = (gidx == 2) ? tanh_fast(gate) : sigmoid_fast(gate);
            act_lds[gidx][t - gidx * H] = a;
        }
        __syncthreads();               // gates ready

        if (t < H) {
            float ig = act_lds[0][t];
            float fg = act_lds[1][t];
            float gg = act_lds[2][t];
            float og = act_lds[3][t];
            c = fg * c + ig * gg;
            h_lds[t] = og * tanh_fast(c);
        }
        __syncthreads();               // h ready for next step
    }

    if (t == 0) {
        float s = b_out[0];
        #pragma unroll 4
        for (int j = 0; j < H; ++j) s += W_out[j] * h_lds[j];
        out[0] = s;
    }
}

extern "C" void kernel_launch(void* const* d_in, const int* in_sizes, int n_in,
                              void* d_out, int out_size, void* d_ws, size_t ws_size,
                              hipStream_t stream) {
    const float* x     = (const float*)d_in[0];
    const float* W_ih  = (const float*)d_in[1];
    const float* W_hh  = (const float*)d_in[2];
    const float* b_ih  = (const float*)d_in[3];
    const float* b_hh  = (const float*)d_in[4];
    const float* W_out = (const float*)d_in[5];
    const float* b_out = (const float*)d_in[6];
    float* out = (float*)d_out;

    lstm_seq_kernel<<<1, 448, 0, stream>>>(x, W_ih, W_hh, b_ih, b_hh,
                                           W_out, b_out, out);
}